// Round 7
// baseline (450.889 us; speedup 1.0000x reference)
//
#include <hip/hip_runtime.h>

// SSIM loss — barrier-free streaming separable conv, v6.
// Dataset so far: v1 (=exact this structure, 1 row/step) 122us is the best;
// every deviation (skew w/ runtime offsets, write-late order, 4-wave blocks,
// SROWS=16, 22-step static unroll) regressed or spilled. Residency is pinned
// at ~5 waves/CU regardless of launch geometry, so the lever is per-wave
// time = steps x per-step serialization. v6 = v1 EXACTLY, except:
//  - TWO rows per step (21 steps, not 42): halves the per-wave count of
//    {vmcnt wait -> LDS write -> LDS read} serialization points; doubles the
//    prefetch flight window (2 rows fetched at step t, staged at t+1).
//    Ring slots stay compile-time static: gcd(2,11)=1 so (2t)%11 = (2*ut)%11
//    in the 11-body unroll, independent of the runtime chunk index.
//  - Fused finalize (proven in v5).
// Kept from v1: interleaved un-skewed LDS ({a,b} per col; conflicts are only
// ~3.5% of step time and static offsets let ds_read2_b64 merge), 1-wave
// blocks (4x16x48 grid), stage->fetch->read->conv order, __launch_bounds__
// (64,2) (NEVER (64,4): v2 spilled the ring; 22-step static unroll: v4 spilled).
// w-windows of the two rows are loaded/consumed SEQUENTIALLY (one w[12] live)
// to keep VGPRs near v1's 100.

typedef float v2f __attribute__((ext_vector_type(2)));

#define IMG    512
#define SCOLS  128          // cols per strip (2 per lane)
#define SROWS  32           // output rows per strip
#define NROWS  42           // staged rows incl halo
#define TSTEPS 21           // 2 rows per step
#define BUFW   288          // (SCOLS + 16 halo cols) * 2 images, interleaved
#define NBLOCKS (4 * 16 * 48)
#define NPIX   (16.0f * 3.0f * 512.0f * 512.0f)

__device__ __forceinline__ float clamp01(float x) {
    // fmaxf(NaN,0) -> 0: nan_to_num + clip(0,1) in two ops
    return fminf(fmaxf(x, 0.0f), 1.0f);
}

__device__ __forceinline__ float ssim_px(v2f mu, v2f e, float e12, float C1, float C2) {
    v2f musq = mu * mu;                       // {mu1^2, mu2^2}  (pk_mul)
    float mu12 = mu.x * mu.y;
    v2f sig = e - musq;                       // {sig1, sig2}
    v2f lo = {1e-6f, 1e-6f};
    v2f hi = {1e6f, 1e6f};
    sig = __builtin_elementwise_max(sig, lo);
    sig = __builtin_elementwise_min(sig, hi);
    float s12 = e12 - mu12;
    float num = fmaf(2.f, mu12, C1) * fmaf(2.f, s12, C2);
    float den = (musq.x + musq.y + C1) * (sig.x + sig.y + C2);  // >= C1*C2 > 0
    return num * __builtin_amdgcn_rcpf(den);
}

__global__ __launch_bounds__(64, 2)
void ssim_stream_kernel(const float* __restrict__ imgA,
                        const float* __restrict__ imgB,
                        float* __restrict__ ws,
                        float* __restrict__ out)
{
    // Gaussian 11-tap, sigma=1.5, normalized (fp64-computed, verified R1)
    constexpr float GW[11] = {
        0.00102838f, 0.00759880f, 0.03600077f, 0.10936070f, 0.21300554f,
        0.26601173f,
        0.21300554f, 0.10936070f, 0.03600077f, 0.00759880f, 0.00102838f
    };
    const float C1 = 1.01e-4f;   // 0.01^2 + 1e-6
    const float C2 = 9.01e-4f;   // 0.03^2 + 1e-6

    // [parity][row-within-pair][word]; each buffer holds rows {2t, 2t+1}
    __shared__ float sbuf[2][2][BUFW];   // 4608 B

    const int lane = threadIdx.x;
    const int C0 = blockIdx.x * SCOLS;
    const int R0 = blockIdx.y * SROWS;
    const size_t pOff = (size_t)blockIdx.z * (size_t)(IMG * IMG);

    // --- staging task decode (constant per lane), v1 layout ---
    // 72 float4 tasks per row: t<36 -> imgA quad t ; t>=36 -> imgB quad t-36.
    // LDS word for col offset xr (= abs col - (C0-8)), img m: 2*xr + m.
    const int t0   = lane;
    const int q0   = (t0 < 36) ? t0 : (t0 - 36);
    const float* sp0 = ((t0 < 36) ? imgA : imgB) + pOff;
    const int col0 = C0 - 8 + 4 * q0;
    const bool okc0 = (col0 >= 0) && (col0 <= IMG - 4);   // quads never straddle edge
    const int wd0  = 8 * q0 + ((t0 < 36) ? 0 : 1);
    const bool has1 = (lane < 8);                          // tasks 64..71: imgB q=28..35
    const int q1   = 28 + lane;
    const int col1 = C0 - 8 + 4 * q1;
    const bool okc1 = (col1 >= 0) && (col1 <= IMG - 4);
    const int wd1  = 8 * q1 + 1;
    const float* sp1 = imgB + pOff;

    // --- register ring: 11 slots x 2 cols x {h1h2 pair, h11h22 pair, h12} ---
    v2f rA[11][2], rB[11][2];
    float rC[11][2];
#pragma unroll
    for (int i = 0; i < 11; ++i) {
        rA[i][0] = 0; rA[i][1] = 0;
        rB[i][0] = 0; rB[i][1] = 0;
        rC[i][0] = 0; rC[i][1] = 0;
    }

    float lsum = 0.f;
    float4 fE0, fE1, fO0, fO1;   // fetched pair of rows (even, odd)

#define FETCH(P0_, P1_, row_) do {                                            \
        const int ir = (row_);                                                \
        const bool okr = (unsigned)ir < (unsigned)IMG;                        \
        P0_ = make_float4(0,0,0,0); P1_ = make_float4(0,0,0,0);               \
        if (okr && okc0) P0_ = *(const float4*)(sp0 + (size_t)ir * IMG + col0);\
        if (has1 && okr && okc1)                                              \
            P1_ = *(const float4*)(sp1 + (size_t)ir * IMG + col1);            \
    } while (0)

#define STAGE(dbase_, P0_, P1_) do {                                          \
        float* d0 = (dbase_) + wd0;                                           \
        d0[0] = clamp01(P0_.x); d0[2] = clamp01(P0_.y);                       \
        d0[4] = clamp01(P0_.z); d0[6] = clamp01(P0_.w);                       \
        if (has1) {                                                           \
            float* d1 = (dbase_) + wd1;                                       \
            d1[0] = clamp01(P1_.x); d1[2] = clamp01(P1_.y);                   \
            d1[4] = clamp01(P1_.z); d1[6] = clamp01(P1_.w);                   \
        }                                                                     \
    } while (0)

// horizontal 11-tap conv of window wv_ -> ring slot SL_ (static index)
#define HCONV(wv_, SL_) do {                                                  \
        v2f hA0 = 0, hB0 = 0, hA1 = 0, hB1 = 0;                               \
        float hC0 = 0, hC1 = 0;                                               \
        _Pragma("unroll")                                                     \
        for (int j = 0; j < 11; ++j) {                                        \
            const float gj = GW[j];                                           \
            v2f w0 = wv_[j], w1 = wv_[j + 1];                                 \
            v2f g0 = gj * w0;            /* {g*a, g*b}   pk_mul */            \
            v2f g1 = gj * w1;                                                 \
            hA0 += g0; hA1 += g1;        /* {h1, h2}     pk_add */            \
            hB0 += g0 * w0;              /* {h11, h22}   pk_fma */            \
            hB1 += g1 * w1;                                                   \
            hC0 = fmaf(g0.x, w0.y, hC0); /* h12          fma    */            \
            hC1 = fmaf(g1.x, w1.y, hC1);                                      \
        }                                                                     \
        rA[SL_][0] = hA0; rA[SL_][1] = hA1;                                   \
        rB[SL_][0] = hB0; rB[SL_][1] = hB1;                                   \
        rC[SL_][0] = hC0; rC[SL_][1] = hC1;                                   \
    } while (0)

// vertical 11-tap conv over ring slots (BASE_+i)%11 + SSIM accumulate
#define VOUT(BASE_) do {                                                      \
        v2f vA0 = 0, vB0 = 0, vA1 = 0, vB1 = 0;                               \
        float vC0 = 0, vC1 = 0;                                               \
        _Pragma("unroll")                                                     \
        for (int i = 0; i < 11; ++i) {                                        \
            const int sl = ((BASE_) + i) % 11;   /* static */                 \
            const float gi = GW[i];                                           \
            vA0 += gi * rA[sl][0]; vA1 += gi * rA[sl][1];                     \
            vB0 += gi * rB[sl][0]; vB1 += gi * rB[sl][1];                     \
            vC0 = fmaf(gi, rC[sl][0], vC0);                                   \
            vC1 = fmaf(gi, rC[sl][1], vC1);                                   \
        }                                                                     \
        lsum += ssim_px(vA0, vB0, vC0, C1, C2);                               \
        lsum += ssim_px(vA1, vB1, vC1, C1, C2);                               \
    } while (0)

    // --- prologue: rows 0,1 -> buf[0]; rows 2,3 in registers ---
    FETCH(fE0, fE1, R0 - 5);        // row 0
    FETCH(fO0, fO1, R0 - 4);        // row 1
    STAGE(&sbuf[0][0][0], fE0, fE1);
    STAGE(&sbuf[0][1][0], fO0, fO1);
    FETCH(fE0, fE1, R0 - 3);        // row 2
    FETCH(fO0, fO1, R0 - 2);        // row 3

#pragma unroll 1
    for (int chunk = 0; chunk < 2; ++chunk) {
#pragma unroll
        for (int ut = 0; ut < 11; ++ut) {
            const int t = chunk * 11 + ut;      // uniform across wave
            const int U0 = (2 * ut) % 11;       // slot of row 2t (static)
            const int U1 = (2 * ut + 1) % 11;   // slot of row 2t+1 (static)
            if (t < TSTEPS) {
                const int par = t & 1;
                const float* sbE = &sbuf[par][0][0];       // row 2t
                const float* sbO = &sbuf[par][1][0];       // row 2t+1
                float* dbE = &sbuf[par ^ 1][0][0];          // gets row 2t+2
                float* dbO = &sbuf[par ^ 1][1][0];          // gets row 2t+3

                // 1. stage rows 2t+2, 2t+3 (fetched last step; vmcnt wait
                //    here had a full step of flight) + issue next fetch.
                if (t + 1 < TSTEPS) {
                    STAGE(dbE, fE0, fE1);
                    STAGE(dbO, fO0, fO1);
                    FETCH(fE0, fE1, R0 - 5 + 2 * t + 4);
                    FETCH(fO0, fO1, R0 - 5 + 2 * t + 5);
                }

                // 2. row 2t: window read (static offsets -> ds_read2_b64),
                //    h-conv -> slot U0
                {
                    const v2f* wp = (const v2f*)sbE + (2 * lane + 3);
                    v2f w[12];
#pragma unroll
                    for (int p = 0; p < 12; ++p) w[p] = wp[p];
                    HCONV(w, U0);
                }

                // 3. out row 2t-10 (needs rows 2t-10..2t; slot of 2t-10 = U1,
                //    which still holds row 2t-10 until step 4 overwrites it)
                if (t >= 5) VOUT(U1);

                // 4. row 2t+1: window read + h-conv -> slot U1
                {
                    const v2f* wp = (const v2f*)sbO + (2 * lane + 3);
                    v2f w[12];
#pragma unroll
                    for (int p = 0; p < 12; ++p) w[p] = wp[p];
                    HCONV(w, U1);
                }

                // 5. out row 2t-9 (rows 2t-9..2t+1; base slot (U1+1)%11)
                if (t >= 5) VOUT(U1 + 1);
            }
        }
    }
#undef VOUT
#undef HCONV
#undef FETCH
#undef STAGE

    // wave64 reduce, one atomic per wave
#pragma unroll
    for (int off = 32; off >= 1; off >>= 1)
        lsum += __shfl_down(lsum, off, 64);

    if (lane == 0) {
        atomicAdd(ws, lsum);
        __threadfence();
        unsigned done = atomicAdd(reinterpret_cast<unsigned*>(ws) + 1, 1u);
        if (done == NBLOCKS - 1) {
            __threadfence();
            float total = atomicAdd(ws, 0.0f);   // coherent read-back
            out[0] = 1.0f - total * (1.0f / NPIX);
        }
    }
}

extern "C" void kernel_launch(void* const* d_in, const int* in_sizes, int n_in,
                              void* d_out, int out_size, void* d_ws, size_t ws_size,
                              hipStream_t stream) {
    const float* img1 = (const float*)d_in[0];
    const float* img2 = (const float*)d_in[1];
    float* out = (float*)d_out;
    float* ws  = (float*)d_ws;

    hipMemsetAsync(ws, 0, 2 * sizeof(float), stream);   // {sum, done-counter}

    dim3 grid(IMG / SCOLS, IMG / SROWS, 48);            // 4 x 16 x 48 = 3072 waves
    ssim_stream_kernel<<<grid, 64, 0, stream>>>(img1, img2, ws, out);
}

// Round 9
// 260.368 us; speedup vs baseline: 1.7317x; 1.7317x over previous
//
#include <hip/hip_runtime.h>

// SSIM loss v7b — vertical-first separable conv, raw-pixel register ring.
// v7 post-mortem: FAILED correctness with run-varying error (0.597 / 468) — a
// race. The LDS h-exchange assumed program-order write->read, but per-thread
// alias analysis only ties the write (slot 3+lane) to the k=3 read; the other
// 6 reads have no per-thread alias, so the compiler may hoist reads above the
// writes (or sink next step's writes into this step's reads). Lockstep HW then
// reads slots before neighbor lanes wrote them. v1 survived the same idiom by
// scheduling luck only.
// v7b fix: __syncthreads() between exchange writes and reads (1-wave block:
// near-free, and its lgkmcnt(0) also forces HW completion), plus a zero-cost
// compiler memory fence after the reads so next step's writes can't move up.
// Unchanged from v7:
//  - ring stores RAW clamped pixels: 11 rows x 2 cols x 2 imgs = 44 regs
//    (vs v1's 110-reg h-sum ring that spilled in v2/v4/v6 and capped occupancy)
//  - 4-deep prefetch queue (8 float2, shift-renamed) -> 4 loads in flight
//  - horizontal conv via 2.8KB LDS exchange of the 5 vertical sums
//  - column halo: 5 overlapping strips (C0 = 116*bx - 6, even -> aligned
//    pairs; pairs never straddle the image edge), outputs masked to the 116
//    valid cols; every global col covered exactly once
//  - fused finalize; __launch_bounds__(64,2) (NEVER (64,4) — v2 spill)

typedef float v2f __attribute__((ext_vector_type(2)));

#define IMG    512
#define OCOLS  116          // valid output cols per strip (local cols [6,122))
#define NSTRIPS 5           // 5*116 = 580 >= 512
#define SROWS  32           // output rows per strip
#define NSTEPS 42           // SROWS + 10 halo rows
#define XPITCH 70           // exchange pairs per quantity: 3 pad + 64 + 3 pad
#define NBLOCKS (NSTRIPS * 16 * 48)
#define NPIX   (16.0f * 3.0f * 512.0f * 512.0f)

__device__ __forceinline__ float clamp01(float x) {
    // fmaxf(NaN,0) -> 0: nan_to_num + clip(0,1) in two ops
    return fminf(fmaxf(x, 0.0f), 1.0f);
}

__device__ __forceinline__ float ssim_px(v2f mu, v2f e, float e12, float C1, float C2) {
    v2f musq = mu * mu;                       // {mu1^2, mu2^2}
    float mu12 = mu.x * mu.y;
    v2f sig = e - musq;                       // {sig1, sig2}
    v2f lo = {1e-6f, 1e-6f};
    v2f hi = {1e6f, 1e6f};
    sig = __builtin_elementwise_max(sig, lo);
    sig = __builtin_elementwise_min(sig, hi);
    float s12 = e12 - mu12;
    float num = fmaf(2.f, mu12, C1) * fmaf(2.f, s12, C2);
    float den = (musq.x + musq.y + C1) * (sig.x + sig.y + C2);  // >= C1*C2 > 0
    return num * __builtin_amdgcn_rcpf(den);
}

__global__ __launch_bounds__(64, 2)
void ssim_stream_kernel(const float* __restrict__ imgA,
                        const float* __restrict__ imgB,
                        float* __restrict__ ws,
                        float* __restrict__ out)
{
    // Gaussian 11-tap, sigma=1.5, normalized (fp64-computed, verified R1)
    constexpr float GW[11] = {
        0.00102838f, 0.00759880f, 0.03600077f, 0.10936070f, 0.21300554f,
        0.26601173f,
        0.21300554f, 0.10936070f, 0.03600077f, 0.00759880f, 0.00102838f
    };
    const float C1 = 1.01e-4f;   // 0.01^2 + 1e-6
    const float C2 = 9.01e-4f;   // 0.03^2 + 1e-6

    // h-exchange buffer: [quantity][pair slot][2 cols]. 2800 B. Pads (slots
    // 0..2, 67..69) are never written; garbage they feed reaches only
    // masked-out output cols.
    __shared__ float xch[5][XPITCH][2];

    const int lane = threadIdx.x;
    const int C0 = blockIdx.x * OCOLS - 6;          // even -> aligned pairs
    const int R0 = blockIdx.y * SROWS;
    const size_t pOff = (size_t)blockIdx.z * (size_t)(IMG * IMG);

    // lane's column pair (c0 even): pair is fully inside or fully outside img
    const int c0 = C0 + 2 * lane;
    const bool okp = (unsigned)c0 < (unsigned)IMG;   // covers c1 = c0+1 too
    const int cb = min(max(c0, 0), IMG - 2);         // clamped, even, aligned
    const int l0 = 2 * lane;                         // local col of .x
    const bool valid0 = (l0     >= 6) && (l0     < 6 + OCOLS) && okp;
    const bool valid1 = (l0 + 1 >= 6) && (l0 + 1 < 6 + OCOLS) && okp;
    const float* const pA = imgA + pOff + cb;
    const float* const pB = imgB + pOff + cb;

    // raw-pixel ring: 11 rows x {a-pair, b-pair} = 44 regs
    v2f rgA[11], rgB[11];
#pragma unroll
    for (int i = 0; i < 11; ++i) { rgA[i] = 0; rgB[i] = 0; }

    float lsum = 0.f;

    // 4-deep prefetch queue (consume head, shift, issue tail)
    float2 qA0, qA1, qA2, qA3, qB0, qB1, qB2, qB3;

#define ISSUE(QA_, QB_, row_) do {                                            \
        const int cr = min(max((row_), 0), IMG - 1);                          \
        QA_ = *(const float2*)(pA + (size_t)cr * IMG);                        \
        QB_ = *(const float2*)(pB + (size_t)cr * IMG);                        \
    } while (0)

    ISSUE(qA0, qB0, R0 - 5);
    ISSUE(qA1, qB1, R0 - 4);
    ISSUE(qA2, qB2, R0 - 3);
    ISSUE(qA3, qB3, R0 - 2);

#pragma unroll 1
    for (int ch = 0; ch < 4; ++ch) {
#pragma unroll
        for (int u = 0; u < 11; ++u) {
            const int s = ch * 11 + u;          // uniform across wave
            if (s < NSTEPS) {
                // 1. consume queue head = input row ir (zero outside image)
                const int ir = R0 - 5 + s;
                const bool rowOk = (unsigned)ir < (unsigned)IMG;
                const bool ok = rowOk && okp;
                v2f a, b;
                a.x = ok ? clamp01(qA0.x) : 0.f;
                a.y = ok ? clamp01(qA0.y) : 0.f;
                b.x = ok ? clamp01(qB0.x) : 0.f;
                b.y = ok ? clamp01(qB0.y) : 0.f;
                rgA[u] = a; rgB[u] = b;

                // 2. shift queue, issue row s+4 (4 rows always in flight)
                qA0 = qA1; qB0 = qB1;
                qA1 = qA2; qB1 = qB2;
                qA2 = qA3; qB2 = qB3;
                ISSUE(qA3, qB3, R0 - 5 + s + 4);

                // 3. vertical sums + h-exchange + horizontal conv + SSIM
                if (s >= 10) {      // wave-uniform -> barrier below is safe
                    // rows s-10..s live in slots (u+1+i)%11 (static)
                    v2f sA = 0, sB = 0, sAA = 0, sBB = 0, sAB = 0;
#pragma unroll
                    for (int i = 0; i < 11; ++i) {
                        const int sl = (u + 1 + i) % 11;
                        const float g = GW[i];
                        v2f ra = rgA[sl], rb = rgB[sl];
                        v2f ga = g * ra, gb = g * rb;
                        sA += ga; sB += gb;
                        sAA += ga * ra;          // E-sum of a^2 (vertical)
                        sBB += gb * rb;
                        sAB += ga * rb;
                    }
                    // exchange the 5 vertical sums (2-way banks = free)
                    *(v2f*)&xch[0][3 + lane][0] = sA;
                    *(v2f*)&xch[1][3 + lane][0] = sB;
                    *(v2f*)&xch[2][3 + lane][0] = sAA;
                    *(v2f*)&xch[3][3 + lane][0] = sBB;
                    *(v2f*)&xch[4][3 + lane][0] = sAB;

                    // RACE FIX: compiler may hoist non-aliasing (per-thread)
                    // reads above the writes. Barrier pins order + completes
                    // writes (lgkmcnt(0)). ~free for a 1-wave block.
                    __syncthreads();

                    // horizontal conv: out0 = local col 2*lane, out1 = +1.
                    float o0[5], o1[5];
#pragma unroll
                    for (int q = 0; q < 5; ++q) {
                        const float* xb = &xch[q][lane][0];  // pair lane-3 (+3 pad)
                        v2f P0 = *(const v2f*)(xb + 0);
                        v2f P1 = *(const v2f*)(xb + 2);
                        v2f P2 = *(const v2f*)(xb + 4);
                        v2f P3 = *(const v2f*)(xb + 6);
                        v2f P4 = *(const v2f*)(xb + 8);
                        v2f P5 = *(const v2f*)(xb + 10);
                        v2f P6 = *(const v2f*)(xb + 12);
                        float t0 = GW[0] * P0.y;             // col 2L-5
                        float t1 = GW[0] * P1.x;             // col 2L-4
                        t0 = fmaf(GW[1], P1.x, t0); t1 = fmaf(GW[1], P1.y, t1);
                        t0 = fmaf(GW[2], P1.y, t0); t1 = fmaf(GW[2], P2.x, t1);
                        t0 = fmaf(GW[3], P2.x, t0); t1 = fmaf(GW[3], P2.y, t1);
                        t0 = fmaf(GW[4], P2.y, t0); t1 = fmaf(GW[4], P3.x, t1);
                        t0 = fmaf(GW[5], P3.x, t0); t1 = fmaf(GW[5], P3.y, t1);
                        t0 = fmaf(GW[6], P3.y, t0); t1 = fmaf(GW[6], P4.x, t1);
                        t0 = fmaf(GW[7], P4.x, t0); t1 = fmaf(GW[7], P4.y, t1);
                        t0 = fmaf(GW[8], P4.y, t0); t1 = fmaf(GW[8], P5.x, t1);
                        t0 = fmaf(GW[9], P5.x, t0); t1 = fmaf(GW[9], P5.y, t1);
                        t0 = fmaf(GW[10], P5.y, t0); t1 = fmaf(GW[10], P6.x, t1);
                        o0[q] = t0; o1[q] = t1;
                    }
                    // RACE FIX: next step's writes must not be scheduled into
                    // this step's read window (zero-cost compiler fence; HW
                    // LDS pipe is in-order per wave).
                    asm volatile("" ::: "memory");

                    // q order: 0=mu1, 1=mu2, 2=E[a^2], 3=E[b^2], 4=E[ab]
                    float s0 = ssim_px((v2f){o0[0], o0[1]},
                                       (v2f){o0[2], o0[3]}, o0[4], C1, C2);
                    float s1 = ssim_px((v2f){o1[0], o1[1]},
                                       (v2f){o1[2], o1[3]}, o1[4], C1, C2);
                    lsum += valid0 ? s0 : 0.f;
                    lsum += valid1 ? s1 : 0.f;
                }
            }
        }
    }
#undef ISSUE

    // wave64 reduce, one atomic per wave
#pragma unroll
    for (int off = 32; off >= 1; off >>= 1)
        lsum += __shfl_down(lsum, off, 64);

    if (lane == 0) {
        atomicAdd(ws, lsum);
        __threadfence();
        unsigned done = atomicAdd(reinterpret_cast<unsigned*>(ws) + 1, 1u);
        if (done == NBLOCKS - 1) {
            __threadfence();
            float total = atomicAdd(ws, 0.0f);   // coherent read-back
            out[0] = 1.0f - total * (1.0f / NPIX);
        }
    }
}

extern "C" void kernel_launch(void* const* d_in, const int* in_sizes, int n_in,
                              void* d_out, int out_size, void* d_ws, size_t ws_size,
                              hipStream_t stream) {
    const float* img1 = (const float*)d_in[0];
    const float* img2 = (const float*)d_in[1];
    float* out = (float*)d_out;
    float* ws  = (float*)d_ws;

    hipMemsetAsync(ws, 0, 2 * sizeof(float), stream);   // {sum, done-counter}

    dim3 grid(NSTRIPS, IMG / SROWS, 48);                // 5 x 16 x 48 = 3840 waves
    ssim_stream_kernel<<<grid, 64, 0, stream>>>(img1, img2, ws, out);
}

// Round 10
// 259.222 us; speedup vs baseline: 1.7394x; 1.0044x over previous
//
#include <hip/hip_runtime.h>

// SSIM loss v8 — v7b + double-buffered exchange, barrier-free pipelined h-conv.
// v7b post-mortem (PASSED, 175us, VGPR 64, 0 bank conflicts, occ 29%): the
// per-step serial chain [v-sum -> 5 LDS writes -> __syncthreads (lgkmcnt(0)
// drain) -> 35 reads (full ~120cy latency exposed) -> h-conv] rides the
// critical path of all 42 steps; VALUBusy 27%, IPC/wave ~0.05, while both
// VALU (~30us) and HBM (~14us) rooflines are 4-6x away.
// v8: xch is double-buffered; step s WRITES v-sums(row s) to xch[s&1] and
// h-convs v-sums(row s-1) from xch[(s&1)^1] (out row s-11); one epilogue
// h-conv finishes row 31. Reads/writes never share a buffer within a step:
//  - NO barrier, NO waitcnt: per-wave in-order DS pipe orders write(s) before
//    read(s+1); read latency overlaps a full step of VALU.
//  - one zero-cost compiler fence per step (asm "" memory) pins issue order
//    across the buffer swap (v7's race was compiler reordering, not HW).
// Unchanged from v7b: raw-pixel 44-reg ring (static slots, 11-unroll),
// 4-deep prefetch queue, 5 overlapping col-strips with masked outputs,
// fused finalize, __launch_bounds__(64,2) (NEVER (64,4) — v2 spill).

typedef float v2f __attribute__((ext_vector_type(2)));

#define IMG    512
#define OCOLS  116          // valid output cols per strip (local cols [6,122))
#define NSTRIPS 5           // 5*116 = 580 >= 512
#define SROWS  32           // output rows per strip
#define NSTEPS 42           // SROWS + 10 halo rows
#define XPITCH 70           // exchange pairs per quantity: 3 pad + 64 + 3 pad
#define QSTRIDE (XPITCH * 2)   // floats between quantities (140)
#define NBLOCKS (NSTRIPS * 16 * 48)
#define NPIX   (16.0f * 3.0f * 512.0f * 512.0f)

__device__ __forceinline__ float clamp01(float x) {
    // fmaxf(NaN,0) -> 0: nan_to_num + clip(0,1) in two ops
    return fminf(fmaxf(x, 0.0f), 1.0f);
}

__device__ __forceinline__ float ssim_px(v2f mu, v2f e, float e12, float C1, float C2) {
    v2f musq = mu * mu;                       // {mu1^2, mu2^2}
    float mu12 = mu.x * mu.y;
    v2f sig = e - musq;                       // {sig1, sig2}
    v2f lo = {1e-6f, 1e-6f};
    v2f hi = {1e6f, 1e6f};
    sig = __builtin_elementwise_max(sig, lo);
    sig = __builtin_elementwise_min(sig, hi);
    float s12 = e12 - mu12;
    float num = fmaf(2.f, mu12, C1) * fmaf(2.f, s12, C2);
    float den = (musq.x + musq.y + C1) * (sig.x + sig.y + C2);  // >= C1*C2 > 0
    return num * __builtin_amdgcn_rcpf(den);
}

__global__ __launch_bounds__(64, 2)
void ssim_stream_kernel(const float* __restrict__ imgA,
                        const float* __restrict__ imgB,
                        float* __restrict__ ws,
                        float* __restrict__ out)
{
    // Gaussian 11-tap, sigma=1.5, normalized (fp64-computed, verified R1)
    constexpr float GW[11] = {
        0.00102838f, 0.00759880f, 0.03600077f, 0.10936070f, 0.21300554f,
        0.26601173f,
        0.21300554f, 0.10936070f, 0.03600077f, 0.00759880f, 0.00102838f
    };
    const float C1 = 1.01e-4f;   // 0.01^2 + 1e-6
    const float C2 = 9.01e-4f;   // 0.03^2 + 1e-6

    // double-buffered h-exchange: [parity][quantity][pair slot][2 cols], 5600B.
    // Pad slots (0..2, 67..69) never written; garbage reaches only masked cols.
    __shared__ float xch[2][5][XPITCH][2];

    const int lane = threadIdx.x;
    const int C0 = blockIdx.x * OCOLS - 6;          // even -> aligned pairs
    const int R0 = blockIdx.y * SROWS;
    const size_t pOff = (size_t)blockIdx.z * (size_t)(IMG * IMG);

    // lane's column pair (c0 even): pair is fully inside or fully outside img
    const int c0 = C0 + 2 * lane;
    const bool okp = (unsigned)c0 < (unsigned)IMG;   // covers c1 = c0+1 too
    const int cb = min(max(c0, 0), IMG - 2);         // clamped, even, aligned
    const int l0 = 2 * lane;                         // local col of .x
    const bool valid0 = (l0     >= 6) && (l0     < 6 + OCOLS) && okp;
    const bool valid1 = (l0 + 1 >= 6) && (l0 + 1 < 6 + OCOLS) && okp;
    const float* const pA = imgA + pOff + cb;
    const float* const pB = imgB + pOff + cb;

    // raw-pixel ring: 11 rows x {a-pair, b-pair} = 44 regs
    v2f rgA[11], rgB[11];
#pragma unroll
    for (int i = 0; i < 11; ++i) { rgA[i] = 0; rgB[i] = 0; }

    float lsum = 0.f;

    // 4-deep prefetch queue (consume head, shift, issue tail)
    float2 qA0, qA1, qA2, qA3, qB0, qB1, qB2, qB3;

#define ISSUE(QA_, QB_, row_) do {                                            \
        const int cr = min(max((row_), 0), IMG - 1);                          \
        QA_ = *(const float2*)(pA + (size_t)cr * IMG);                        \
        QB_ = *(const float2*)(pB + (size_t)cr * IMG);                        \
    } while (0)

// h-conv of the 5 quantities from exchange buffer base xr_ + SSIM accumulate
#define HOUT(xr_) do {                                                        \
        float o0[5], o1[5];                                                   \
        _Pragma("unroll")                                                     \
        for (int q = 0; q < 5; ++q) {                                         \
            const float* xb = (xr_) + q * QSTRIDE;    /* pair lane-3 (+3 pad) */ \
            v2f P0 = *(const v2f*)(xb + 0);                                   \
            v2f P1 = *(const v2f*)(xb + 2);                                   \
            v2f P2 = *(const v2f*)(xb + 4);                                   \
            v2f P3 = *(const v2f*)(xb + 6);                                   \
            v2f P4 = *(const v2f*)(xb + 8);                                   \
            v2f P5 = *(const v2f*)(xb + 10);                                  \
            v2f P6 = *(const v2f*)(xb + 12);                                  \
            float t0 = GW[0] * P0.y;             /* col 2L-5 */               \
            float t1 = GW[0] * P1.x;             /* col 2L-4 */               \
            t0 = fmaf(GW[1], P1.x, t0); t1 = fmaf(GW[1], P1.y, t1);           \
            t0 = fmaf(GW[2], P1.y, t0); t1 = fmaf(GW[2], P2.x, t1);           \
            t0 = fmaf(GW[3], P2.x, t0); t1 = fmaf(GW[3], P2.y, t1);           \
            t0 = fmaf(GW[4], P2.y, t0); t1 = fmaf(GW[4], P3.x, t1);           \
            t0 = fmaf(GW[5], P3.x, t0); t1 = fmaf(GW[5], P3.y, t1);           \
            t0 = fmaf(GW[6], P3.y, t0); t1 = fmaf(GW[6], P4.x, t1);           \
            t0 = fmaf(GW[7], P4.x, t0); t1 = fmaf(GW[7], P4.y, t1);           \
            t0 = fmaf(GW[8], P4.y, t0); t1 = fmaf(GW[8], P5.x, t1);           \
            t0 = fmaf(GW[9], P5.x, t0); t1 = fmaf(GW[9], P5.y, t1);           \
            t0 = fmaf(GW[10], P5.y, t0); t1 = fmaf(GW[10], P6.x, t1);         \
            o0[q] = t0; o1[q] = t1;                                           \
        }                                                                     \
        /* q order: 0=mu1, 1=mu2, 2=E[a^2], 3=E[b^2], 4=E[ab] */              \
        float s0 = ssim_px((v2f){o0[0], o0[1]},                               \
                           (v2f){o0[2], o0[3]}, o0[4], C1, C2);               \
        float s1 = ssim_px((v2f){o1[0], o1[1]},                               \
                           (v2f){o1[2], o1[3]}, o1[4], C1, C2);               \
        lsum += valid0 ? s0 : 0.f;                                            \
        lsum += valid1 ? s1 : 0.f;                                            \
    } while (0)

    ISSUE(qA0, qB0, R0 - 5);
    ISSUE(qA1, qB1, R0 - 4);
    ISSUE(qA2, qB2, R0 - 3);
    ISSUE(qA3, qB3, R0 - 2);

#pragma unroll 1
    for (int ch = 0; ch < 4; ++ch) {
#pragma unroll
        for (int u = 0; u < 11; ++u) {
            const int s = ch * 11 + u;          // uniform across wave
            if (s < NSTEPS) {
                // 1. consume queue head = input row (zero outside image)
                const int ir = R0 - 5 + s;
                const bool ok = ((unsigned)ir < (unsigned)IMG) && okp;
                v2f a, b;
                a.x = ok ? clamp01(qA0.x) : 0.f;
                a.y = ok ? clamp01(qA0.y) : 0.f;
                b.x = ok ? clamp01(qB0.x) : 0.f;
                b.y = ok ? clamp01(qB0.y) : 0.f;
                rgA[u] = a; rgB[u] = b;

                // 2. shift queue, issue row s+4 (4 rows always in flight)
                qA0 = qA1; qB0 = qB1;
                qA1 = qA2; qB1 = qB2;
                qA2 = qA3; qB2 = qB3;
                ISSUE(qA3, qB3, R0 - 5 + s + 4);

                // 3. v-sums of rows s-10..s -> write xch[s&1]
                if (s >= 10) {
                    v2f sA = 0, sB = 0, sAA = 0, sBB = 0, sAB = 0;
#pragma unroll
                    for (int i = 0; i < 11; ++i) {
                        const int sl = (u + 1 + i) % 11;   // static
                        const float g = GW[i];
                        v2f ra = rgA[sl], rb = rgB[sl];
                        v2f ga = g * ra, gb = g * rb;
                        sA += ga; sB += gb;
                        sAA += ga * ra;
                        sBB += gb * rb;
                        sAB += ga * rb;
                    }
                    float* xw = &xch[s & 1][0][3 + lane][0];
                    *(v2f*)(xw + 0 * QSTRIDE) = sA;
                    *(v2f*)(xw + 1 * QSTRIDE) = sB;
                    *(v2f*)(xw + 2 * QSTRIDE) = sAA;
                    *(v2f*)(xw + 3 * QSTRIDE) = sBB;
                    *(v2f*)(xw + 4 * QSTRIDE) = sAB;
                }

                // 4. h-conv of row s-1 (other buffer; written last step and
                //    ordered by the per-wave in-order DS pipe) -> out row s-11
                if (s >= 11) {
                    const float* xr = &xch[(s & 1) ^ 1][0][lane][0];
                    HOUT(xr);
                }

                // compiler fence: reads of step s must not sink below step
                // s+1's writes (same buffer), and s+1's reads must not hoist
                // above this step's writes. Zero runtime cost.
                asm volatile("" ::: "memory");
            }
        }
    }

    // epilogue: out row 31 from v-sums written at s=41 (buffer 1)
    {
        const float* xr = &xch[1][0][lane][0];
        HOUT(xr);
    }
#undef HOUT
#undef ISSUE

    // wave64 reduce, one atomic per wave
#pragma unroll
    for (int off = 32; off >= 1; off >>= 1)
        lsum += __shfl_down(lsum, off, 64);

    if (lane == 0) {
        atomicAdd(ws, lsum);
        __threadfence();
        unsigned done = atomicAdd(reinterpret_cast<unsigned*>(ws) + 1, 1u);
        if (done == NBLOCKS - 1) {
            __threadfence();
            float total = atomicAdd(ws, 0.0f);   // coherent read-back
            out[0] = 1.0f - total * (1.0f / NPIX);
        }
    }
}

extern "C" void kernel_launch(void* const* d_in, const int* in_sizes, int n_in,
                              void* d_out, int out_size, void* d_ws, size_t ws_size,
                              hipStream_t stream) {
    const float* img1 = (const float*)d_in[0];
    const float* img2 = (const float*)d_in[1];
    float* out = (float*)d_out;
    float* ws  = (float*)d_ws;

    hipMemsetAsync(ws, 0, 2 * sizeof(float), stream);   // {sum, done-counter}

    dim3 grid(NSTRIPS, IMG / SROWS, 48);                // 5 x 16 x 48 = 3840 waves
    ssim_stream_kernel<<<grid, 64, 0, stream>>>(img1, img2, ws, out);
}